// Round 2
// baseline (301.984 us; speedup 1.0000x reference)
//
#include <hip/hip_runtime.h>
#include <hip/hip_bf16.h>

// VectorQuantizer on MI355X — two-phase exact-argmin design.
// Phase 1: bf16x2-split MFMA distance GEMM, fused top-2 argmin per row.
//          Rows whose approx top-2 gap < THRESH are flagged (the reference's
//          fp32 pipeline quantizes d to ~3e-5 at magnitude ~256; only those
//          rows are rounding/tie-sensitive).
// Phase 2: flagged rows only — recompute all 1024 distances emulating the
//          numpy fp32 pipeline exactly (fp64-exact dot -> fp32, A=fl(zn+en),
//          d=fl(A-2t)), argmin with lowest-index tie-break; overwrite index
//          and z_q row.
// d_out: z_q (B,C,T,H,W) 8388608 f32, then indices (B,T,H,W) 32768 as f32.

#define DEVI __device__ __forceinline__

typedef __attribute__((ext_vector_type(8))) short bf16x8;   // 8 bf16 in 4 VGPRs
typedef __attribute__((ext_vector_type(4))) float f32x4;

#define C_DIM   256
#define K_CODES 1024
#define S_DIM   8192          // T*H*W
#define N_ROWS  32768
#define ZQ_ELEMS 8388608      // B*C*S
#define TILE_M  64
#define CHUNK   64
#define NCHUNK  16
#define THRESH  1.3e-4f       // > 2*(ulp@256) + 2*max split-dot err, 2x margin

DEVI unsigned short f2b(float f) {                 // fp32 -> bf16 RNE
    unsigned u = __float_as_uint(f);
    u += 0x7FFFu + ((u >> 16) & 1u);
    return (unsigned short)(u >> 16);
}
DEVI float b2f(unsigned short h) { return __uint_as_float(((unsigned)h) << 16); }

// ---------------- prologue: split codebook into bf16 hi/lo + row norms ----
__global__ void vq_prep_e(const float* __restrict__ E,
                          unsigned short* __restrict__ ehi,
                          unsigned short* __restrict__ elo,
                          float* __restrict__ e2) {
    const int k = blockIdx.x;          // 1024 blocks
    const int lane = threadIdx.x;      // 64 threads
    const float4 v = reinterpret_cast<const float4*>(E + (size_t)k * C_DIM)[lane];
    float s = v.x * v.x + v.y * v.y + v.z * v.z + v.w * v.w;
    ushort4 h, l;
    h.x = f2b(v.x); l.x = f2b(v.x - b2f(h.x));
    h.y = f2b(v.y); l.y = f2b(v.y - b2f(h.y));
    h.z = f2b(v.z); l.z = f2b(v.z - b2f(h.z));
    h.w = f2b(v.w); l.w = f2b(v.w - b2f(h.w));
    reinterpret_cast<ushort4*>(ehi + (size_t)k * C_DIM)[lane] = h;
    reinterpret_cast<ushort4*>(elo + (size_t)k * C_DIM)[lane] = l;
#pragma unroll
    for (int m = 32; m; m >>= 1) s += __shfl_xor(s, m, 64);
    if (lane == 0) e2[k] = s;
}

// ---------------- phase 1: fused distance GEMM + top-2 argmin ----------------
#define OFF_AHI 0
#define OFF_ALO 32768
#define OFF_BHI 65536
#define OFF_BLO 98304

struct SmemGemm { unsigned short t[4 * 64 * 256]; };   // 131072 B

DEVI bf16x8 ldsfrag(const char* L, int arroff, int row, int coff) {
    const int byte = arroff + row * 512 + (coff ^ ((row & 7) << 4));
    return *reinterpret_cast<const bf16x8*>(L + byte);
}

__global__ __launch_bounds__(256) void vq_main(
        const float* __restrict__ z, const float* __restrict__ E,
        const unsigned short* __restrict__ ehi,
        const unsigned short* __restrict__ elo,
        const float* __restrict__ e2g,
        float* __restrict__ out_zq, float* __restrict__ out_idx,
        int* __restrict__ cnt, int* __restrict__ list) {
    __shared__ __align__(16) union USm {
        SmemGemm g;
        float zq[64][257];        // epilogue transpose buffer (re-use)
    } sm;
    __shared__ float e2ch[64];
    __shared__ float redD1[2][64], redD2[2][64];
    __shared__ int   redK1[2][64], redK2[2][64];
    __shared__ int   kfin[64];

    char* L = reinterpret_cast<char*>(&sm);
    const int tid = threadIdx.x;
    const int n0 = blockIdx.x * TILE_M;
    const int b  = n0 >> 13;          // / 8192
    const int s0 = n0 & (S_DIM - 1);

    // ---- stage A tile: z rows n0..n0+63, converted fp32 -> bf16 hi/lo ----
    {
        const int s  = tid & 63;
        const int cg = tid >> 6;                       // 0..3
        const float* zb = z + (size_t)b * (C_DIM * S_DIM) + s0 + s;
#pragma unroll
        for (int ci = 0; ci < 16; ++ci) {
            const int c = cg * 4 + ci * 16;
            const float x0 = zb[(size_t)(c + 0) * S_DIM];
            const float x1 = zb[(size_t)(c + 1) * S_DIM];
            const float x2 = zb[(size_t)(c + 2) * S_DIM];
            const float x3 = zb[(size_t)(c + 3) * S_DIM];
            ushort4 h, l;
            h.x = f2b(x0); l.x = f2b(x0 - b2f(h.x));
            h.y = f2b(x1); l.y = f2b(x1 - b2f(h.y));
            h.z = f2b(x2); l.z = f2b(x2 - b2f(h.z));
            h.w = f2b(x3); l.w = f2b(x3 - b2f(h.w));
            const int byte = s * 512 + ((c * 2) ^ ((s & 7) << 4));
            *reinterpret_cast<ushort4*>(L + OFF_AHI + byte) = h;
            *reinterpret_cast<ushort4*>(L + OFF_ALO + byte) = l;
        }
    }

    const int w    = tid >> 6;
    const int lane = tid & 63;
    const int wm   = w >> 1, wn = w & 1;
    const int q    = lane >> 4, jj = lane & 15;
    const int arow = wm * 32 + jj;
    const int brow = wn * 32 + jj;

    float bd1[8], bd2[8];
    int   bk1[8], bk2[8];
#pragma unroll
    for (int i = 0; i < 8; ++i) {
        bd1[i] = 3.402823466e+38f; bd2[i] = 3.402823466e+38f;
        bk1[i] = 0; bk2[i] = 0;
    }

    for (int ch = 0; ch < NCHUNK; ++ch) {
        const int kb = ch * CHUNK;
        __syncthreads();
        {   // stage B chunk (bf16 from ws), swizzled
            const uint4* ghi = reinterpret_cast<const uint4*>(ehi + (size_t)kb * C_DIM);
            const uint4* glo = reinterpret_cast<const uint4*>(elo + (size_t)kb * C_DIM);
#pragma unroll
            for (int i = 0; i < 8; ++i) {
                const int u = i * 256 + tid;
                const int row = u >> 5;
                const int coff = (u & 31) << 4;
                const int byte = row * 512 + (coff ^ ((row & 7) << 4));
                uint4 vh = ghi[u];
                *reinterpret_cast<uint4*>(L + OFF_BHI + byte) = vh;
                uint4 vl = glo[u];
                *reinterpret_cast<uint4*>(L + OFF_BLO + byte) = vl;
            }
            if (tid < 64) e2ch[tid] = e2g[kb + tid];
        }
        __syncthreads();

        f32x4 a00 = {0.f, 0.f, 0.f, 0.f};
        f32x4 a01 = a00, a10 = a00, a11 = a00;
#pragma unroll
        for (int ks = 0; ks < 8; ++ks) {
            const int coff = ks * 64 + q * 16;
            const bf16x8 ah0 = ldsfrag(L, OFF_AHI, arow,      coff);
            const bf16x8 ah1 = ldsfrag(L, OFF_AHI, arow + 16, coff);
            const bf16x8 al0 = ldsfrag(L, OFF_ALO, arow,      coff);
            const bf16x8 al1 = ldsfrag(L, OFF_ALO, arow + 16, coff);
            const bf16x8 bh0 = ldsfrag(L, OFF_BHI, brow,      coff);
            const bf16x8 bh1 = ldsfrag(L, OFF_BHI, brow + 16, coff);
            const bf16x8 bl0 = ldsfrag(L, OFF_BLO, brow,      coff);
            const bf16x8 bl1 = ldsfrag(L, OFF_BLO, brow + 16, coff);
            a00 = __builtin_amdgcn_mfma_f32_16x16x32_bf16(ah0, bh0, a00, 0, 0, 0);
            a01 = __builtin_amdgcn_mfma_f32_16x16x32_bf16(ah0, bh1, a01, 0, 0, 0);
            a10 = __builtin_amdgcn_mfma_f32_16x16x32_bf16(ah1, bh0, a10, 0, 0, 0);
            a11 = __builtin_amdgcn_mfma_f32_16x16x32_bf16(ah1, bh1, a11, 0, 0, 0);
            a00 = __builtin_amdgcn_mfma_f32_16x16x32_bf16(ah0, bl0, a00, 0, 0, 0);
            a01 = __builtin_amdgcn_mfma_f32_16x16x32_bf16(ah0, bl1, a01, 0, 0, 0);
            a10 = __builtin_amdgcn_mfma_f32_16x16x32_bf16(ah1, bl0, a10, 0, 0, 0);
            a11 = __builtin_amdgcn_mfma_f32_16x16x32_bf16(ah1, bl1, a11, 0, 0, 0);
            a00 = __builtin_amdgcn_mfma_f32_16x16x32_bf16(al0, bh0, a00, 0, 0, 0);
            a01 = __builtin_amdgcn_mfma_f32_16x16x32_bf16(al0, bh1, a01, 0, 0, 0);
            a10 = __builtin_amdgcn_mfma_f32_16x16x32_bf16(al1, bh0, a10, 0, 0, 0);
            a11 = __builtin_amdgcn_mfma_f32_16x16x32_bf16(al1, bh1, a11, 0, 0, 0);
        }

        // score + running top-2 (d = |e|^2 - 2 z.e ; |z|^2 constant per row)
#define UPD(ACC, FM, FN)                                                      \
        { const int lc = wn * 32 + (FN) * 16 + jj;                            \
          const float e2v = e2ch[lc];                                         \
          const int code = kb + lc;                                           \
          _Pragma("unroll")                                                   \
          for (int r = 0; r < 4; ++r) {                                       \
              const float d = __builtin_fmaf(-2.f, ACC[r], e2v);              \
              const int sl = (FM) * 4 + r;                                    \
              if (d < bd1[sl]) { bd2[sl] = bd1[sl]; bk2[sl] = bk1[sl];        \
                                 bd1[sl] = d; bk1[sl] = code; }               \
              else if (d < bd2[sl]) { bd2[sl] = d; bk2[sl] = code; }          \
          } }
        UPD(a00, 0, 0) UPD(a01, 0, 1) UPD(a10, 1, 0) UPD(a11, 1, 1)
#undef UPD
    }

    // ---- top-2 reduce across the 16 lanes sharing each output row ----
#pragma unroll
    for (int fm = 0; fm < 2; ++fm) {
#pragma unroll
        for (int r = 0; r < 4; ++r) {
            const int sl = fm * 4 + r;
            float d1 = bd1[sl], d2 = bd2[sl];
            int   k1 = bk1[sl], k2 = bk2[sl];
#pragma unroll
            for (int m = 1; m < 16; m <<= 1) {
                const float e1 = __shfl_xor(d1, m, 64);
                const float eo = __shfl_xor(d2, m, 64);
                const int   j1 = __shfl_xor(k1, m, 64);
                const int   j2 = __shfl_xor(k2, m, 64);
                if (e1 < d1 || (e1 == d1 && j1 < k1)) {
                    if (d1 < eo || (d1 == eo && k1 < j2)) { d2 = d1; k2 = k1; }
                    else                                   { d2 = eo; k2 = j2; }
                    d1 = e1; k1 = j1;
                } else if (e1 < d2 || (e1 == d2 && j1 < k2)) { d2 = e1; k2 = j1; }
            }
            if (jj == 0) {
                const int row = wm * 32 + fm * 16 + q * 4 + r;
                redD1[wn][row] = d1; redK1[wn][row] = k1;
                redD2[wn][row] = d2; redK2[wn][row] = k2;
            }
        }
    }
    __syncthreads();
    if (tid < 64) {
        const float d1a = redD1[0][tid], d2a = redD2[0][tid];
        const int   k1a = redK1[0][tid], k2a = redK2[0][tid];
        const float d1b = redD1[1][tid], d2b = redD2[1][tid];
        const int   k1b = redK1[1][tid], k2b = redK2[1][tid];
        float d1, d2; int k1, k2;
        if (d1b < d1a || (d1b == d1a && k1b < k1a)) {
            d1 = d1b; k1 = k1b;
            if (d1a < d2b || (d1a == d2b && k1a < k2b)) { d2 = d1a; k2 = k1a; }
            else                                         { d2 = d2b; k2 = k2b; }
        } else {
            d1 = d1a; k1 = k1a;
            if (d1b < d2a || (d1b == d2a && k1b < k2a)) { d2 = d1b; k2 = k1b; }
            else                                         { d2 = d2a; k2 = k2a; }
        }
        kfin[tid] = k1;
        out_idx[n0 + tid] = (float)k1;      // provisional (final for unflagged)
        if (d2 - d1 < THRESH) {             // rounding/tie-sensitive row
            const int p = atomicAdd(cnt, 1);
            list[p] = n0 + tid;
        }
    }
    __syncthreads();

    // ---- epilogue: gather selected code rows -> LDS transpose -> z_q ----
    {
        const int slot = tid >> 2;             // 0..63 (row in tile)
        const int cs   = (tid & 3) << 6;       // 0,64,128,192
        const int kk   = kfin[slot];
        const float4* er = reinterpret_cast<const float4*>(E + (size_t)kk * C_DIM + cs);
#pragma unroll
        for (int i = 0; i < 16; ++i) {
            const float4 v = er[i];
            float* zr = &sm.zq[slot][cs + 4 * i];
            zr[0] = v.x; zr[1] = v.y; zr[2] = v.z; zr[3] = v.w;
        }
    }
    __syncthreads();
    {
        const int s  = tid & 63;
        const int cg = tid >> 6;
        float* ob = out_zq + (size_t)b * (C_DIM * S_DIM) + s0 + s;
#pragma unroll
        for (int i = 0; i < 64; ++i) {
            const int c = cg * 64 + i;
            ob[(size_t)c * S_DIM] = sm.zq[s][c];
        }
    }
}

// ---------------- phase 2: exact-pipeline recheck of flagged rows ----------
__global__ __launch_bounds__(256) void vq_fix(
        const float* __restrict__ z, const float* __restrict__ E,
        const int* __restrict__ cnt, const int* __restrict__ list,
        float* __restrict__ out_zq, float* __restrict__ out_idx) {
    __shared__ double zrowd[256];
    __shared__ float  sD[256];
    __shared__ int    sK[256];
    __shared__ float  znS;

    const int tid = threadIdx.x;
    const int count = cnt[0];

    for (int ri = blockIdx.x; ri < count; ri += gridDim.x) {
        const int n = list[ri];
        const int b = n >> 13, s = n & (S_DIM - 1);

        __syncthreads();   // guard LDS reuse across row iterations
        zrowd[tid] = (double)z[((size_t)(b * C_DIM + tid)) * S_DIM + s];
        __syncthreads();
        if (tid < 64) {    // znorm: fp64-exact sum -> fp32 (order-invariant
            double zn = 0.0;                 //  vs numpy via ulp-shift argument)
#pragma unroll
            for (int i = 0; i < 4; ++i) {
                const double v = zrowd[tid * 4 + i];
                zn = fma(v, v, zn);
            }
#pragma unroll
            for (int m = 1; m < 64; m <<= 1) zn += __shfl_xor(zn, m, 64);
            if (tid == 0) znS = (float)zn;
        }
        __syncthreads();
        const float znorm = znS;

        float bd = 3.402823466e+38f; int bk = 0;
        for (int kq = 0; kq < 4; ++kq) {
            const int k = kq * 256 + tid;
            const float4* er = reinterpret_cast<const float4*>(E + (size_t)k * C_DIM);
            double dot = 0.0, e2 = 0.0;
#pragma unroll 8
            for (int i = 0; i < 64; ++i) {
                const float4 v = er[i];
                const double ex = v.x, ey = v.y, ez = v.z, ew = v.w;
                dot = fma(zrowd[4 * i + 0], ex, dot);
                dot = fma(zrowd[4 * i + 1], ey, dot);
                dot = fma(zrowd[4 * i + 2], ez, dot);
                dot = fma(zrowd[4 * i + 3], ew, dot);
                e2  = fma(ex, ex, e2);
                e2  = fma(ey, ey, e2);
                e2  = fma(ez, ez, e2);
                e2  = fma(ew, ew, e2);
            }
            // numpy fp32 pipeline: A = fl(znorm + enorm); d = fl(A - 2*fl(dot))
            const float t = (float)dot;
            const float A = znorm + (float)e2;
            const float d = A - 2.0f * t;
            if (d < bd || (d == bd && k < bk)) { bd = d; bk = k; }  // k ascending
        }
        sD[tid] = bd; sK[tid] = bk;
        __syncthreads();
        for (int o = 128; o; o >>= 1) {
            if (tid < o) {
                const float d2 = sD[tid + o]; const int k2 = sK[tid + o];
                if (d2 < sD[tid] || (d2 == sD[tid] && k2 < sK[tid])) {
                    sD[tid] = d2; sK[tid] = k2;
                }
            }
            __syncthreads();
        }
        const int kk = sK[0];
        if (tid == 0) out_idx[n] = (float)kk;
        out_zq[((size_t)(b * C_DIM + tid)) * S_DIM + s] = E[(size_t)kk * C_DIM + tid];
    }
}

extern "C" void kernel_launch(void* const* d_in, const int* in_sizes, int n_in,
                              void* d_out, int out_size, void* d_ws, size_t ws_size,
                              hipStream_t stream) {
    (void)in_sizes; (void)n_in; (void)out_size; (void)ws_size;
    const float* z = (const float*)d_in[0];
    const float* E = (const float*)d_in[1];
    // ws layout: ehi [256K bf16], elo [256K bf16], e2 [1024 f32],
    //            cnt [1 int], list [32768 int]
    char* wsb = (char*)d_ws;
    unsigned short* ehi = (unsigned short*)(wsb);
    unsigned short* elo = (unsigned short*)(wsb + 524288);
    float* e2  = (float*)(wsb + 1048576);
    int*   cnt = (int*)  (wsb + 1052672);
    int*   list= (int*)  (wsb + 1052676);
    float* out = (float*)d_out;

    hipMemsetAsync(cnt, 0, sizeof(int), stream);
    vq_prep_e<<<dim3(K_CODES), dim3(64), 0, stream>>>(E, ehi, elo, e2);
    vq_main<<<dim3(N_ROWS / TILE_M), dim3(256), 0, stream>>>(
        z, E, ehi, elo, e2, out, out + ZQ_ELEMS, cnt, list);
    vq_fix<<<dim3(256), dim3(256), 0, stream>>>(
        z, E, cnt, list, out, out + ZQ_ELEMS);
}

// Round 3
// 286.384 us; speedup vs baseline: 1.0545x; 1.0545x over previous
//
#include <hip/hip_runtime.h>
#include <hip/hip_bf16.h>

// VectorQuantizer on MI355X — two-phase exact-argmin, pipelined MFMA phase 1.
// Phase 1: bf16x2-split MFMA distance GEMM (3 passes hh+hl+lh), A-frags in
//          registers, B double-buffered in LDS (1 barrier/chunk, prefetch
//          overlapped with compute), fused top-2 argmin per row. Rows with
//          approx top-2 gap < THRESH flagged (reference's fp32 pipeline
//          quantizes d at ~3e-5 @ magnitude 256).
// Phase 2: flagged rows only — exact numpy-fp32-pipeline emulation via fp64
//          dots; one row per block.
// d_out: z_q (B,C,T,H,W) 8388608 f32, then indices (B,T,H,W) 32768 as f32.

#define DEVI __device__ __forceinline__

typedef __attribute__((ext_vector_type(8))) short bf16x8;
typedef __attribute__((ext_vector_type(4))) float f32x4;

#define C_DIM   256
#define K_CODES 1024
#define S_DIM   8192
#define N_ROWS  32768
#define ZQ_ELEMS 8388608
#define TILE_M  64
#define CHUNK   32
#define NCHUNK  32
#define THRESH  1.3e-4f
#define FLT_BIG 3.402823466e+38f

DEVI unsigned short f2b(float f) {                 // fp32 -> bf16 RNE
    unsigned u = __float_as_uint(f);
    u += 0x7FFFu + ((u >> 16) & 1u);
    return (unsigned short)(u >> 16);
}
DEVI float b2f(unsigned short h) { return __uint_as_float(((unsigned)h) << 16); }

DEVI f32x4 MF(bf16x8 a, bf16x8 b, f32x4 c) {
    return __builtin_amdgcn_mfma_f32_16x16x32_bf16(a, b, c, 0, 0, 0);
}

// swizzled LDS fragment read: tile row stride 512B, 16B-slot XOR (row&7)
DEVI bf16x8 ldsfrag(const char* L, int arroff, int row, int coff) {
    const int byte = arroff + row * 512 + (coff ^ ((row & 7) << 4));
    return *reinterpret_cast<const bf16x8*>(L + byte);
}

// ---------------- prologue: split codebook into bf16 hi/lo + row norms ----
__global__ void vq_prep_e(const float* __restrict__ E,
                          unsigned short* __restrict__ ehi,
                          unsigned short* __restrict__ elo,
                          float* __restrict__ e2) {
    const int k = blockIdx.x;          // 1024 blocks
    const int lane = threadIdx.x;      // 64 threads
    const float4 v = reinterpret_cast<const float4*>(E + (size_t)k * C_DIM)[lane];
    float s = v.x * v.x + v.y * v.y + v.z * v.z + v.w * v.w;
    ushort4 h, l;
    h.x = f2b(v.x); l.x = f2b(v.x - b2f(h.x));
    h.y = f2b(v.y); l.y = f2b(v.y - b2f(h.y));
    h.z = f2b(v.z); l.z = f2b(v.z - b2f(h.z));
    h.w = f2b(v.w); l.w = f2b(v.w - b2f(h.w));
    reinterpret_cast<ushort4*>(ehi + (size_t)k * C_DIM)[lane] = h;
    reinterpret_cast<ushort4*>(elo + (size_t)k * C_DIM)[lane] = l;
#pragma unroll
    for (int m = 32; m; m >>= 1) s += __shfl_xor(s, m, 64);
    if (lane == 0) e2[k] = s;
}

// ---------------- phase 1 ----------------
// LDS: smraw 64KB. First used as A-stage ([64][256] bf16 hi @0, lo @32768),
// then as B double-buffer (buf p @ p*32768: hi 16KB + lo 16KB per 32-code
// chunk), finally as epilogue f32 [64][256] transpose buffer.
__global__ __launch_bounds__(256, 2) void vq_main(
        const float* __restrict__ z, const float* __restrict__ E,
        const unsigned short* __restrict__ ehi,
        const unsigned short* __restrict__ elo,
        const float* __restrict__ e2g,
        float* __restrict__ out_zq, float* __restrict__ out_idx,
        int* __restrict__ cnt, int* __restrict__ list) {
    __shared__ __align__(16) char smraw[65536];
    __shared__ float redD1[2][64], redD2[2][64];
    __shared__ int   redK1[2][64];
    __shared__ int   kfin[64];

    const int tid = threadIdx.x;
    const int n0 = blockIdx.x * TILE_M;
    const int b  = n0 >> 13;
    const int s0 = n0 & (S_DIM - 1);

    // ---- stage A tile: z rows n0..n0+63, fp32 -> bf16 hi/lo, swizzled ----
    {
        const int s  = tid & 63;
        const int cg = tid >> 6;
        const float* zb = z + (size_t)b * (C_DIM * S_DIM) + s0 + s;
#pragma unroll
        for (int ci = 0; ci < 16; ++ci) {
            const int c = cg * 4 + ci * 16;
            const float x0 = zb[(size_t)(c + 0) * S_DIM];
            const float x1 = zb[(size_t)(c + 1) * S_DIM];
            const float x2 = zb[(size_t)(c + 2) * S_DIM];
            const float x3 = zb[(size_t)(c + 3) * S_DIM];
            ushort4 h, l;
            h.x = f2b(x0); l.x = f2b(x0 - b2f(h.x));
            h.y = f2b(x1); l.y = f2b(x1 - b2f(h.y));
            h.z = f2b(x2); l.z = f2b(x2 - b2f(h.z));
            h.w = f2b(x3); l.w = f2b(x3 - b2f(h.w));
            const int byte = s * 512 + ((c * 2) ^ ((s & 7) << 4));
            *reinterpret_cast<ushort4*>(smraw + byte) = h;
            *reinterpret_cast<ushort4*>(smraw + 32768 + byte) = l;
        }
    }
    __syncthreads();

    const int w    = tid >> 6;
    const int lane = tid & 63;
    const int wm   = w >> 1, wn = w & 1;   // wave tile: rows wm*32+.., cols wn*16+..
    const int q    = lane >> 4, jj = lane & 15;

    // ---- A fragments to registers (2 row-tiles x hi/lo x 8 ks) ----
    bf16x8 Ah0[8], Ah1[8], Al0[8], Al1[8];
    {
        const int r0 = wm * 32 + jj, r1 = r0 + 16;
#pragma unroll
        for (int ks = 0; ks < 8; ++ks) {
            const int coff = ks * 64 + q * 16;
            Ah0[ks] = ldsfrag(smraw, 0,     r0, coff);
            Ah1[ks] = ldsfrag(smraw, 0,     r1, coff);
            Al0[ks] = ldsfrag(smraw, 32768, r0, coff);
            Al1[ks] = ldsfrag(smraw, 32768, r1, coff);
        }
    }

    // ---- B staging constants (per thread) ----
    const int srow  = tid >> 5;          // base row 0..7 (i adds 8)
    const int sslot = tid & 31;          // 16B slot within 512B row
    const int lbase = srow * 512 + ((sslot << 4) ^ ((srow & 7) << 4));
    const int gbase = srow * 32 + sslot; // uint4 units
    const uint4* Ghi = reinterpret_cast<const uint4*>(ehi);
    const uint4* Glo = reinterpret_cast<const uint4*>(elo);

    uint4 gh[4], gl[4];
#pragma unroll
    for (int i = 0; i < 4; ++i) {        // prefetch chunk 0
        gh[i] = Ghi[gbase + i * 256];
        gl[i] = Glo[gbase + i * 256];
    }
    __syncthreads();                     // all A-frag reads done -> reuse smraw
#pragma unroll
    for (int i = 0; i < 4; ++i) {        // write chunk 0 -> buf0
        *reinterpret_cast<uint4*>(smraw + lbase + i * 4096)         = gh[i];
        *reinterpret_cast<uint4*>(smraw + 16384 + lbase + i * 4096) = gl[i];
    }

    float bd1[8], bd2[8];
    int   bk1[8];
#pragma unroll
    for (int i = 0; i < 8; ++i) { bd1[i] = FLT_BIG; bd2[i] = FLT_BIG; bk1[i] = 0; }

    const int browbyte = (wn * 16 + jj) * 512;
    const int t0x = (q * 16) ^ ((jj & 7) << 4);
    const int mycol = wn * 16 + jj;

    for (int n = 0; n < NCHUNK; ++n) {
        const int kb = n * CHUNK;
        if (n + 1 < NCHUNK) {            // prefetch chunk n+1 (global->reg)
            const int gof = (kb + CHUNK) * 32 + gbase;
#pragma unroll
            for (int i = 0; i < 4; ++i) {
                gh[i] = Ghi[gof + i * 256];
                gl[i] = Glo[gof + i * 256];
            }
        }
        __syncthreads();                 // buf[n&1] fully written, prev reads done

        const char* Lb = smraw + (n & 1) * 32768 + browbyte;
        f32x4 acc0 = {0.f, 0.f, 0.f, 0.f}, acc1 = acc0;
#pragma unroll
        for (int ks = 0; ks < 8; ++ks) {
            const int off = (ks * 64) ^ t0x;
            const bf16x8 bh = *reinterpret_cast<const bf16x8*>(Lb + off);
            const bf16x8 bl = *reinterpret_cast<const bf16x8*>(Lb + off + 16384);
            acc0 = MF(Ah0[ks], bh, acc0); acc1 = MF(Ah1[ks], bh, acc1);
            acc0 = MF(Ah0[ks], bl, acc0); acc1 = MF(Ah1[ks], bl, acc1);
            acc0 = MF(Al0[ks], bh, acc0); acc1 = MF(Al1[ks], bh, acc1);
        }

        const float e2v = e2g[kb + mycol];
        const int   code = kb + mycol;
#pragma unroll
        for (int r = 0; r < 4; ++r) {
            const float d0 = __builtin_fmaf(-2.f, acc0[r], e2v);
            bd2[r]   = fminf(bd2[r], fmaxf(bd1[r], d0));
            bk1[r]   = (d0 < bd1[r]) ? code : bk1[r];
            bd1[r]   = fminf(bd1[r], d0);
            const float d1 = __builtin_fmaf(-2.f, acc1[r], e2v);
            bd2[4+r] = fminf(bd2[4+r], fmaxf(bd1[4+r], d1));
            bk1[4+r] = (d1 < bd1[4+r]) ? code : bk1[4+r];
            bd1[4+r] = fminf(bd1[4+r], d1);
        }

        if (n + 1 < NCHUNK) {            // write prefetched chunk -> other buf
            char* Lw = smraw + ((n + 1) & 1) * 32768;
#pragma unroll
            for (int i = 0; i < 4; ++i) {
                *reinterpret_cast<uint4*>(Lw + lbase + i * 4096)         = gh[i];
                *reinterpret_cast<uint4*>(Lw + 16384 + lbase + i * 4096) = gl[i];
            }
        }
    }

    // ---- top-2 reduce across the 16 jj-lanes of each row ----
#pragma unroll
    for (int t = 0; t < 2; ++t) {
#pragma unroll
        for (int r = 0; r < 4; ++r) {
            const int sl = t * 4 + r;
            float d1 = bd1[sl], d2 = bd2[sl];
            int   k1 = bk1[sl];
#pragma unroll
            for (int m = 1; m < 16; m <<= 1) {
                const float e1 = __shfl_xor(d1, m, 64);
                const float eo = __shfl_xor(d2, m, 64);
                const int   j1 = __shfl_xor(k1, m, 64);
                const float nd2 = fminf(fminf(d2, eo), fmaxf(d1, e1));
                const bool take = (e1 < d1) || (e1 == d1 && j1 < k1);
                d1 = take ? e1 : d1; k1 = take ? j1 : k1; d2 = nd2;
            }
            if (jj == 0) {
                const int row = wm * 32 + t * 16 + q * 4 + r;
                redD1[wn][row] = d1; redK1[wn][row] = k1; redD2[wn][row] = d2;
            }
        }
    }
    __syncthreads();
    if (tid < 64) {     // merge the two wn col-halves
        const float d1a = redD1[0][tid], d1b = redD1[1][tid];
        const float d2a = redD2[0][tid], d2b = redD2[1][tid];
        const int   k1a = redK1[0][tid], k1b = redK1[1][tid];
        const bool take = (d1b < d1a) || (d1b == d1a && k1b < k1a);
        const float d1 = take ? d1b : d1a;
        const int   k1 = take ? k1b : k1a;
        const float d2 = fminf(fminf(d2a, d2b), fmaxf(d1a, d1b));
        kfin[tid] = k1;
        out_idx[n0 + tid] = (float)k1;
        if (d2 - d1 < THRESH) {
            const int p = atomicAdd(cnt, 1);
            list[p] = n0 + tid;
        }
    }
    __syncthreads();

    // ---- epilogue: gather code rows -> swizzled LDS [64][256] f32 -> z_q ----
    {
        const int slot = tid >> 2;
        const int cs   = (tid & 3) << 6;
        const int kk   = kfin[slot];
        const float4* er = reinterpret_cast<const float4*>(E + (size_t)kk * C_DIM + cs);
        const int rswz = (slot & 7) << 4;
#pragma unroll
        for (int i = 0; i < 16; ++i) {
            const int cbyte = (cs + i * 4) * 4;
            *reinterpret_cast<float4*>(smraw + slot * 1024 + (cbyte ^ rswz)) = er[i];
        }
    }
    __syncthreads();
    {
        const int s  = tid & 63;
        const int cg = tid >> 6;
        float* ob = out_zq + (size_t)b * (C_DIM * S_DIM) + s0 + s;
        const int rswz = (s & 7) << 4;
#pragma unroll
        for (int i = 0; i < 16; ++i) {
            const int c0 = cg * 64 + i * 4;
            const float4 v = *reinterpret_cast<const float4*>(
                smraw + s * 1024 + ((c0 * 4) ^ rswz));
            ob[(size_t)(c0 + 0) * S_DIM] = v.x;
            ob[(size_t)(c0 + 1) * S_DIM] = v.y;
            ob[(size_t)(c0 + 2) * S_DIM] = v.z;
            ob[(size_t)(c0 + 3) * S_DIM] = v.w;
        }
    }
}

// ---------------- phase 2: exact-pipeline recheck of flagged rows ----------
__global__ __launch_bounds__(256) void vq_fix(
        const float* __restrict__ z, const float* __restrict__ E,
        const int* __restrict__ cnt, const int* __restrict__ list,
        float* __restrict__ out_zq, float* __restrict__ out_idx) {
    __shared__ double zrowd[256];
    __shared__ float  sD[256];
    __shared__ int    sK[256];
    __shared__ float  znS;

    const int tid = threadIdx.x;
    const int count = cnt[0];

    for (int ri = blockIdx.x; ri < count; ri += gridDim.x) {
        const int n = list[ri];
        const int b = n >> 13, s = n & (S_DIM - 1);

        __syncthreads();
        zrowd[tid] = (double)z[((size_t)(b * C_DIM + tid)) * S_DIM + s];
        __syncthreads();
        if (tid < 64) {    // znorm: fp64-exact -> fp32
            double zn = 0.0;
#pragma unroll
            for (int i = 0; i < 4; ++i) {
                const double v = zrowd[tid * 4 + i];
                zn = fma(v, v, zn);
            }
#pragma unroll
            for (int m = 1; m < 64; m <<= 1) zn += __shfl_xor(zn, m, 64);
            if (tid == 0) znS = (float)zn;
        }
        __syncthreads();
        const float znorm = znS;

        float bd = FLT_BIG; int bk = 0;
        for (int kq = 0; kq < 4; ++kq) {
            const int k = kq * 256 + tid;
            const float4* er = reinterpret_cast<const float4*>(E + (size_t)k * C_DIM);
            double dot = 0.0, e2 = 0.0;
#pragma unroll 8
            for (int i = 0; i < 64; ++i) {
                const float4 v = er[i];
                const double ex = v.x, ey = v.y, ez = v.z, ew = v.w;
                dot = fma(zrowd[4 * i + 0], ex, dot);
                dot = fma(zrowd[4 * i + 1], ey, dot);
                dot = fma(zrowd[4 * i + 2], ez, dot);
                dot = fma(zrowd[4 * i + 3], ew, dot);
                e2  = fma(ex, ex, e2);
                e2  = fma(ey, ey, e2);
                e2  = fma(ez, ez, e2);
                e2  = fma(ew, ew, e2);
            }
            const float t = (float)dot;
            const float A = znorm + (float)e2;
            const float d = A - 2.0f * t;
            if (d < bd || (d == bd && k < bk)) { bd = d; bk = k; }
        }
        sD[tid] = bd; sK[tid] = bk;
        __syncthreads();
        for (int o = 128; o; o >>= 1) {
            if (tid < o) {
                const float d2 = sD[tid + o]; const int k2 = sK[tid + o];
                if (d2 < sD[tid] || (d2 == sD[tid] && k2 < sK[tid])) {
                    sD[tid] = d2; sK[tid] = k2;
                }
            }
            __syncthreads();
        }
        const int kk = sK[0];
        if (tid == 0) out_idx[n] = (float)kk;
        out_zq[((size_t)(b * C_DIM + tid)) * S_DIM + s] = E[(size_t)kk * C_DIM + tid];
    }
}

extern "C" void kernel_launch(void* const* d_in, const int* in_sizes, int n_in,
                              void* d_out, int out_size, void* d_ws, size_t ws_size,
                              hipStream_t stream) {
    (void)in_sizes; (void)n_in; (void)out_size; (void)ws_size;
    const float* z = (const float*)d_in[0];
    const float* E = (const float*)d_in[1];
    char* wsb = (char*)d_ws;
    unsigned short* ehi = (unsigned short*)(wsb);
    unsigned short* elo = (unsigned short*)(wsb + 524288);
    float* e2  = (float*)(wsb + 1048576);
    int*   cnt = (int*)  (wsb + 1052672);
    int*   list= (int*)  (wsb + 1052676);
    float* out = (float*)d_out;

    hipMemsetAsync(cnt, 0, sizeof(int), stream);
    vq_prep_e<<<dim3(K_CODES), dim3(64), 0, stream>>>(E, ehi, elo, e2);
    vq_main<<<dim3(N_ROWS / TILE_M), dim3(256), 0, stream>>>(
        z, E, ehi, elo, e2, out, out + ZQ_ELEMS, cnt, list);
    vq_fix<<<dim3(1024), dim3(256), 0, stream>>>(
        z, E, cnt, list, out, out + ZQ_ELEMS);
}

// Round 4
// 135.947 us; speedup vs baseline: 2.2213x; 2.1066x over previous
//
#include <hip/hip_runtime.h>
#include <hip/hip_bf16.h>

// VectorQuantizer on MI355X — MFMA distance GEMM + exact-pipeline candidate
// resolution, fused in one main kernel.
// Phase 1: bf16x2-split MFMA (hh+hl+lh), A-frags in registers, B staged by
//          global_load_lds from a PRE-SWIZZLED ws copy (linear DMA -> swizzled
//          LDS layout), double-buffered, 1 barrier/chunk.
// Phase 1.5 (in-block): per-row top-2-with-keys dumped to LDS; leader finds
//          winner + candidates within BAND; multi-candidate rows resolved by
//          fp64-exact dot -> numpy-fp32-pipeline emulation (d = fl(fl(zn+en)
//          - 2*fl(dot)), lowest-index ties). Lane-collision/overflow rows
//          (~2%) go to the vq_fix fallback kernel.
// d_out: z_q (B,C,T,H,W) 8388608 f32, then indices (B,T,H,W) 32768 as f32.

#define DEVI __device__ __forceinline__

typedef __attribute__((ext_vector_type(8))) short bf16x8;
typedef __attribute__((ext_vector_type(4))) float f32x4;

#define C_DIM   256
#define K_CODES 1024
#define S_DIM   8192
#define N_ROWS  32768
#define ZQ_ELEMS 8388608
#define TILE_M  64
#define CHUNK   32
#define NCHUNK  32
#define BAND    4.0e-5f      // ulp(256)=3.05e-5 reversal zone + 2*split-err + margin
#define FLT_BIG 3.402823466e+38f

DEVI unsigned short f2b(float f) {                 // fp32 -> bf16 RNE
    unsigned u = __float_as_uint(f);
    u += 0x7FFFu + ((u >> 16) & 1u);
    return (unsigned short)(u >> 16);
}
DEVI float b2f(unsigned short h) { return __uint_as_float(((unsigned)h) << 16); }

DEVI f32x4 MF(bf16x8 a, bf16x8 b, f32x4 c) {
    return __builtin_amdgcn_mfma_f32_16x16x32_bf16(a, b, c, 0, 0, 0);
}

// swizzled LDS fragment read: row stride 512B, 16B-slot XOR (row&7)
DEVI bf16x8 ldsfrag(const char* L, int arroff, int row, int coff) {
    const int byte = arroff + row * 512 + (coff ^ ((row & 7) << 4));
    return *reinterpret_cast<const bf16x8*>(L + byte);
}

DEVI void gll16(const void* g, void* l) {          // 16B global -> LDS DMA
    __builtin_amdgcn_global_load_lds(
        (const __attribute__((address_space(1))) unsigned int*)g,
        (__attribute__((address_space(3))) unsigned int*)l, 16, 0, 0);
}

// ---- prologue: codebook -> bf16 hi/lo, PRE-SWIZZLED for global_load_lds ----
// ws layout per code row (512B): 16B slot sigma stored at phys (sigma ^ (k&7)).
__global__ void vq_prep_e(const float* __restrict__ E,
                          unsigned short* __restrict__ ehi,
                          unsigned short* __restrict__ elo,
                          float* __restrict__ e2) {
    const int k = blockIdx.x;          // 1024 blocks
    const int lane = threadIdx.x;      // 64 threads; handles logical 8B piece
    const float4 v = reinterpret_cast<const float4*>(E + (size_t)k * C_DIM)[lane];
    float s = v.x * v.x + v.y * v.y + v.z * v.z + v.w * v.w;
    ushort4 h, l;
    h.x = f2b(v.x); l.x = f2b(v.x - b2f(h.x));
    h.y = f2b(v.y); l.y = f2b(v.y - b2f(h.y));
    h.z = f2b(v.z); l.z = f2b(v.z - b2f(h.z));
    h.w = f2b(v.w); l.w = f2b(v.w - b2f(h.w));
    const int phys8 = ((((lane >> 1) ^ (k & 7)) << 1) | (lane & 1));
    reinterpret_cast<ushort4*>(ehi + (size_t)k * C_DIM)[phys8] = h;
    reinterpret_cast<ushort4*>(elo + (size_t)k * C_DIM)[phys8] = l;
#pragma unroll
    for (int m = 32; m; m >>= 1) s += __shfl_xor(s, m, 64);
    if (lane == 0) e2[k] = s;
}

// ---------------- main fused kernel ----------------
__global__ __launch_bounds__(256, 2) void vq_main(
        const float* __restrict__ z, const float* __restrict__ E,
        const unsigned short* __restrict__ ehi,
        const unsigned short* __restrict__ elo,
        const float* __restrict__ e2g,
        float* __restrict__ out_zq, float* __restrict__ out_idx,
        int* __restrict__ gcnt, int* __restrict__ glist) {
    // smraw: A-stage (64KB) -> B dbuf (2x32KB) -> top2 dump (33.8KB)
    //        -> z-f32 stage [64][257] (65.8KB) -> epilogue transpose (64KB)
    __shared__ __align__(16) char smraw[65792];
    __shared__ float e2lds[1024];
    __shared__ float znS[64];
    __shared__ int   candK[64][8];
    __shared__ float tresA[64][8];
    __shared__ float eresA[64][8];
    __shared__ int   kfinA[64];
    __shared__ int   units[384];
    __shared__ int   ucnt;

    const int tid = threadIdx.x;
    const int n0 = blockIdx.x * TILE_M;
    const int b  = n0 >> 13;
    const int s0 = n0 & (S_DIM - 1);

    // ---- e2 -> LDS (once) ----
    reinterpret_cast<float4*>(e2lds)[tid] = reinterpret_cast<const float4*>(e2g)[tid];

    // ---- stage A tile: z rows n0..n0+63, fp32 -> bf16 hi/lo, swizzled ----
    {
        const int s  = tid & 63;
        const int cg = tid >> 6;
        const float* zb = z + (size_t)b * (C_DIM * S_DIM) + s0 + s;
#pragma unroll
        for (int ci = 0; ci < 16; ++ci) {
            const int c = cg * 4 + ci * 16;
            const float x0 = zb[(size_t)(c + 0) * S_DIM];
            const float x1 = zb[(size_t)(c + 1) * S_DIM];
            const float x2 = zb[(size_t)(c + 2) * S_DIM];
            const float x3 = zb[(size_t)(c + 3) * S_DIM];
            ushort4 h, l;
            h.x = f2b(x0); l.x = f2b(x0 - b2f(h.x));
            h.y = f2b(x1); l.y = f2b(x1 - b2f(h.y));
            h.z = f2b(x2); l.z = f2b(x2 - b2f(h.z));
            h.w = f2b(x3); l.w = f2b(x3 - b2f(h.w));
            const int byte = s * 512 + ((c * 2) ^ ((s & 7) << 4));
            *reinterpret_cast<ushort4*>(smraw + byte) = h;
            *reinterpret_cast<ushort4*>(smraw + 32768 + byte) = l;
        }
    }
    __syncthreads();

    const int w    = tid >> 6;
    const int lane = tid & 63;
    const int wm   = w >> 1, wn = w & 1;   // wave: rows wm*32+16x2, cols wn*16
    const int q    = lane >> 4, jj = lane & 15;

    // ---- A fragments to registers (2 row-tiles x hi/lo x 8 ks) ----
    bf16x8 Ah0[8], Ah1[8], Al0[8], Al1[8];
    {
        const int r0 = wm * 32 + jj, r1 = r0 + 16;
#pragma unroll
        for (int ks = 0; ks < 8; ++ks) {
            const int coff = ks * 64 + q * 16;
            Ah0[ks] = ldsfrag(smraw, 0,     r0, coff);
            Ah1[ks] = ldsfrag(smraw, 0,     r1, coff);
            Al0[ks] = ldsfrag(smraw, 32768, r0, coff);
            Al1[ks] = ldsfrag(smraw, 32768, r1, coff);
        }
    }
    __syncthreads();                       // A reads done -> smraw reusable

    // ---- B staging via global_load_lds (pre-swizzled source) ----
    // per chunk: 32 codes -> hi 16KB @ buf+0, lo 16KB @ buf+16384.
    // unit j = w*8+i in 0..31: 1KB each (2 code rows).
#define STAGEB(CH, BUF)                                                       \
    { const size_t coff_ = (size_t)(CH) * 16384;                              \
      _Pragma("unroll")                                                       \
      for (int i_ = 0; i_ < 8; ++i_) {                                        \
          const int j_ = w * 8 + i_;                                          \
          const char* src_ = (const char*)(j_ < 16 ? ehi : elo) + coff_ +     \
                             (size_t)(j_ & 15) * 1024 + (size_t)lane * 16;    \
          char* dst_ = smraw + (BUF) * 32768 + (j_ < 16 ? 0 : 16384) +        \
                       (j_ & 15) * 1024;                                      \
          gll16(src_, dst_);                                                  \
      } }

    STAGEB(0, 0)

    float bd1[8], bd2[8];
    int   bk1[8], bk2[8];
#pragma unroll
    for (int i = 0; i < 8; ++i) {
        bd1[i] = FLT_BIG; bd2[i] = FLT_BIG; bk1[i] = 0; bk2[i] = 0;
    }

    const int browbyte = (wn * 16 + jj) * 512;
    const int t0x = (q * 16) ^ ((jj & 7) << 4);
    const int mycol = wn * 16 + jj;

    for (int n = 0; n < NCHUNK; ++n) {
        const int kb = n * CHUNK;
        __syncthreads();                   // drains gll(chunk n); prev compute done
        if (n + 1 < NCHUNK) STAGEB(n + 1, ((n + 1) & 1))

        const char* Lb = smraw + (n & 1) * 32768 + browbyte;
        f32x4 acc0 = {0.f, 0.f, 0.f, 0.f}, acc1 = acc0;
#pragma unroll
        for (int ks = 0; ks < 8; ++ks) {
            const int off = (ks * 64) ^ t0x;
            const bf16x8 bh = *reinterpret_cast<const bf16x8*>(Lb + off);
            const bf16x8 bl = *reinterpret_cast<const bf16x8*>(Lb + off + 16384);
            acc0 = MF(Ah0[ks], bh, acc0); acc1 = MF(Ah1[ks], bh, acc1);
            acc0 = MF(Ah0[ks], bl, acc0); acc1 = MF(Ah1[ks], bl, acc1);
            acc0 = MF(Al0[ks], bh, acc0); acc1 = MF(Al1[ks], bh, acc1);
        }

        const float e2v = e2lds[kb + mycol];
        const int   code = kb + mycol;
#pragma unroll
        for (int r = 0; r < 4; ++r) {
            {
                const float d = __builtin_fmaf(-2.f, acc0[r], e2v);
                const bool c1 = d < bd1[r];
                const bool c2 = d < bd2[r];
                bd2[r] = c1 ? bd1[r] : (c2 ? d : bd2[r]);
                bk2[r] = c1 ? bk1[r] : (c2 ? code : bk2[r]);
                bd1[r] = c1 ? d : bd1[r];
                bk1[r] = c1 ? code : bk1[r];
            }
            {
                const int sl = 4 + r;
                const float d = __builtin_fmaf(-2.f, acc1[r], e2v);
                const bool c1 = d < bd1[sl];
                const bool c2 = d < bd2[sl];
                bd2[sl] = c1 ? bd1[sl] : (c2 ? d : bd2[sl]);
                bk2[sl] = c1 ? bk1[sl] : (c2 ? code : bk2[sl]);
                bd1[sl] = c1 ? d : bd1[sl];
                bk1[sl] = c1 ? code : bk1[sl];
            }
        }
    }

    // ---- dump per-lane top-2 (row stride 528B to break bank conflicts) ----
    __syncthreads();                       // all compute done -> smraw reusable
    if (tid == 0) ucnt = 0;
#pragma unroll
    for (int t = 0; t < 2; ++t) {
#pragma unroll
        for (int r = 0; r < 4; ++r) {
            const int sl = t * 4 + r;
            const int row = wm * 32 + t * 16 + q * 4 + r;
            int4 v;
            v.x = __float_as_int(bd1[sl]); v.y = bk1[sl];
            v.z = __float_as_int(bd2[sl]); v.w = bk2[sl];
            *reinterpret_cast<int4*>(smraw + row * 528 + (wn * 16 + jj) * 16) = v;
        }
    }
    __syncthreads();

    // ---- leader selection: winner + candidate set within BAND ----
    int rowcnt = 0;                        // leader-persistent
    if (tid < 64) {
        const int row = tid;
        const char* dmp = smraw + row * 528;
        float dmin = FLT_BIG; int kmin = 0x7fffffff;
#pragma unroll 4
        for (int e = 0; e < 32; ++e) {
            const int4 v = *reinterpret_cast<const int4*>(dmp + e * 16);
            const float d1 = __int_as_float(v.x);
            if (d1 < dmin || (d1 == dmin && v.y < kmin)) { dmin = d1; kmin = v.y; }
        }
        const float lim = dmin + BAND;
        int cnt = 0; bool fb = false;
#pragma unroll 4
        for (int e = 0; e < 32; ++e) {
            const int4 v = *reinterpret_cast<const int4*>(dmp + e * 16);
            const float d1 = __int_as_float(v.x);
            const float d2 = __int_as_float(v.z);
            if (d2 <= lim) fb = true;      // lane may hide a 3rd in-band code
            if (d1 <= lim && v.y != kmin) {
                if (cnt < 4) candK[row][1 + cnt] = v.y;
                ++cnt;
            }
        }
        if (cnt > 4) fb = true;
        kfinA[row] = kmin;                 // provisional/final
        if (fb) {
            const int p = atomicAdd(gcnt, 1);
            glist[p] = n0 + row;
            rowcnt = 0;
        } else if (cnt > 0) {
            candK[row][0] = kmin;
            const int base = atomicAdd(&ucnt, cnt + 2);
            units[base] = row * 8 + 7;                       // znorm unit
            for (int i = 0; i <= cnt; ++i) units[base + 1 + i] = row * 8 + i;
            rowcnt = cnt;
        }
    }
    __syncthreads();

    // ---- stage z rows as f32 into LDS (stride 257 floats, 2-way banks) ----
    {
        const int s  = tid & 63;
        const int cg = tid >> 6;
        const float* zb = z + (size_t)b * (C_DIM * S_DIM) + s0 + s;
        char* zl = smraw + s * 1028;
#pragma unroll
        for (int ci = 0; ci < 16; ++ci) {
            const int c = cg * 4 + ci * 16;
            const float x0 = zb[(size_t)(c + 0) * S_DIM];
            const float x1 = zb[(size_t)(c + 1) * S_DIM];
            const float x2 = zb[(size_t)(c + 2) * S_DIM];
            const float x3 = zb[(size_t)(c + 3) * S_DIM];
            *reinterpret_cast<float*>(zl + (c + 0) * 4) = x0;
            *reinterpret_cast<float*>(zl + (c + 1) * 4) = x1;
            *reinterpret_cast<float*>(zl + (c + 2) * 4) = x2;
            *reinterpret_cast<float*>(zl + (c + 3) * 4) = x3;
        }
    }
    __syncthreads();

    // ---- eval units: fp64-exact dot / znorm ----
    {
        const int nu = ucnt;
        for (int u = tid; u < nu; u += 256) {
            const int enc = units[u];
            const int row = enc >> 3, slot = enc & 7;
            const float* zr = reinterpret_cast<const float*>(smraw + row * 1028);
            if (slot == 7) {               // znorm: fp64 sum -> fp32 once
                double a0 = 0.0, a1 = 0.0, a2 = 0.0, a3 = 0.0;
#pragma unroll 8
                for (int c = 0; c < 256; c += 4) {
                    const double v0 = zr[c], v1 = zr[c+1], v2 = zr[c+2], v3 = zr[c+3];
                    a0 = fma(v0, v0, a0); a1 = fma(v1, v1, a1);
                    a2 = fma(v2, v2, a2); a3 = fma(v3, v3, a3);
                }
                znS[row] = (float)((a0 + a1) + (a2 + a3));
            } else {
                const int k = candK[row][slot];
                const float4* er = reinterpret_cast<const float4*>(E + (size_t)k * C_DIM);
                double d0 = 0.0, d1 = 0.0, d2 = 0.0, d3 = 0.0;
                double e0 = 0.0, e1 = 0.0, e2s = 0.0, e3 = 0.0;
#pragma unroll 8
                for (int i = 0; i < 64; ++i) {
                    const float4 v = er[i];
                    const int c = i * 4;
                    const double ex = v.x, ey = v.y, ez = v.z, ew = v.w;
                    d0 = fma((double)zr[c+0], ex, d0); e0 = fma(ex, ex, e0);
                    d1 = fma((double)zr[c+1], ey, d1); e1 = fma(ey, ey, e1);
                    d2 = fma((double)zr[c+2], ez, d2); e2s = fma(ez, ez, e2s);
                    d3 = fma((double)zr[c+3], ew, d3); e3 = fma(ew, ew, e3);
                }
                tresA[row][slot] = (float)((d0 + d1) + (d2 + d3));
                eresA[row][slot] = (float)((e0 + e1) + (e2s + e3));
            }
        }
    }
    __syncthreads();

    // ---- finalize: numpy pipeline d = fl(fl(zn+en) - 2t), lex argmin ----
    if (tid < 64) {
        const int row = tid;
        if (rowcnt > 0) {
            const float zn = znS[row];
            float bdd = FLT_BIG; int bkk = 0x7fffffff;
            for (int i = 0; i <= rowcnt; ++i) {
                const float A = zn + eresA[row][i];
                const float d = A - 2.0f * tresA[row][i];
                const int   k = candK[row][i];
                if (d < bdd || (d == bdd && k < bkk)) { bdd = d; bkk = k; }
            }
            kfinA[row] = bkk;
        }
        out_idx[n0 + row] = (float)kfinA[row];
    }
    __syncthreads();

    // ---- epilogue: gather code rows -> swizzled LDS [64][256] f32 -> z_q ----
    {
        const int slot = tid >> 2;
        const int cs   = (tid & 3) << 6;
        const int kk   = kfinA[slot];
        const float4* er = reinterpret_cast<const float4*>(E + (size_t)kk * C_DIM + cs);
        const int rswz = (slot & 7) << 4;
#pragma unroll
        for (int i = 0; i < 16; ++i) {
            const int cbyte = (cs + i * 4) * 4;
            *reinterpret_cast<float4*>(smraw + slot * 1024 + (cbyte ^ rswz)) = er[i];
        }
    }
    __syncthreads();
    {
        const int s  = tid & 63;
        const int cg = tid >> 6;
        float* ob = out_zq + (size_t)b * (C_DIM * S_DIM) + s0 + s;
        const int rswz = (s & 7) << 4;
#pragma unroll
        for (int i = 0; i < 16; ++i) {
            const int c0 = cg * 64 + i * 4;
            const float4 v = *reinterpret_cast<const float4*>(
                smraw + s * 1024 + ((c0 * 4) ^ rswz));
            ob[(size_t)(c0 + 0) * S_DIM] = v.x;
            ob[(size_t)(c0 + 1) * S_DIM] = v.y;
            ob[(size_t)(c0 + 2) * S_DIM] = v.z;
            ob[(size_t)(c0 + 3) * S_DIM] = v.w;
        }
    }
}

// ---------------- fallback: exact full-row recheck (rare rows) ----------
__global__ __launch_bounds__(256) void vq_fix(
        const float* __restrict__ z, const float* __restrict__ E,
        const int* __restrict__ cnt, const int* __restrict__ list,
        float* __restrict__ out_zq, float* __restrict__ out_idx) {
    __shared__ double zrowd[256];
    __shared__ float  sD[256];
    __shared__ int    sK[256];
    __shared__ float  znS1;

    const int tid = threadIdx.x;
    const int count = cnt[0];

    for (int ri = blockIdx.x; ri < count; ri += gridDim.x) {
        const int n = list[ri];
        const int b = n >> 13, s = n & (S_DIM - 1);

        __syncthreads();
        zrowd[tid] = (double)z[((size_t)(b * C_DIM + tid)) * S_DIM + s];
        __syncthreads();
        if (tid < 64) {
            double zn = 0.0;
#pragma unroll
            for (int i = 0; i < 4; ++i) {
                const double v = zrowd[tid * 4 + i];
                zn = fma(v, v, zn);
            }
#pragma unroll
            for (int m = 1; m < 64; m <<= 1) zn += __shfl_xor(zn, m, 64);
            if (tid == 0) znS1 = (float)zn;
        }
        __syncthreads();
        const float znorm = znS1;

        float bd = FLT_BIG; int bk = 0;
        for (int kq = 0; kq < 4; ++kq) {
            const int k = kq * 256 + tid;
            const float4* er = reinterpret_cast<const float4*>(E + (size_t)k * C_DIM);
            double dot = 0.0, e2 = 0.0;
#pragma unroll 8
            for (int i = 0; i < 64; ++i) {
                const float4 v = er[i];
                const double ex = v.x, ey = v.y, ez = v.z, ew = v.w;
                dot = fma(zrowd[4 * i + 0], ex, dot);
                dot = fma(zrowd[4 * i + 1], ey, dot);
                dot = fma(zrowd[4 * i + 2], ez, dot);
                dot = fma(zrowd[4 * i + 3], ew, dot);
                e2  = fma(ex, ex, e2);
                e2  = fma(ey, ey, e2);
                e2  = fma(ez, ez, e2);
                e2  = fma(ew, ew, e2);
            }
            const float t = (float)dot;
            const float A = znorm + (float)e2;
            const float d = A - 2.0f * t;
            if (d < bd || (d == bd && k < bk)) { bd = d; bk = k; }
        }
        sD[tid] = bd; sK[tid] = bk;
        __syncthreads();
        for (int o = 128; o; o >>= 1) {
            if (tid < o) {
                const float d2 = sD[tid + o]; const int k2 = sK[tid + o];
                if (d2 < sD[tid] || (d2 == sD[tid] && k2 < sK[tid])) {
                    sD[tid] = d2; sK[tid] = k2;
                }
            }
            __syncthreads();
        }
        const int kk = sK[0];
        if (tid == 0) out_idx[n] = (float)kk;
        out_zq[((size_t)(b * C_DIM + tid)) * S_DIM + s] = E[(size_t)kk * C_DIM + tid];
    }
}

extern "C" void kernel_launch(void* const* d_in, const int* in_sizes, int n_in,
                              void* d_out, int out_size, void* d_ws, size_t ws_size,
                              hipStream_t stream) {
    (void)in_sizes; (void)n_in; (void)out_size; (void)ws_size;
    const float* z = (const float*)d_in[0];
    const float* E = (const float*)d_in[1];
    char* wsb = (char*)d_ws;
    unsigned short* ehi = (unsigned short*)(wsb);            // pre-swizzled
    unsigned short* elo = (unsigned short*)(wsb + 524288);   // pre-swizzled
    float* e2   = (float*)(wsb + 1048576);
    int*   cnt  = (int*)  (wsb + 1052672);
    int*   list = (int*)  (wsb + 1052676);
    float* out  = (float*)d_out;

    hipMemsetAsync(cnt, 0, sizeof(int), stream);
    vq_prep_e<<<dim3(K_CODES), dim3(64), 0, stream>>>(E, ehi, elo, e2);
    vq_main<<<dim3(N_ROWS / TILE_M), dim3(256), 0, stream>>>(
        z, E, ehi, elo, e2, out, out + ZQ_ELEMS, cnt, list);
    vq_fix<<<dim3(1024), dim3(256), 0, stream>>>(
        z, E, cnt, list, out, out + ZQ_ELEMS);
}